// Round 4
// baseline (316.531 us; speedup 1.0000x reference)
//
#include <hip/hip_runtime.h>
#include <hip/hip_bf16.h>

// ---------------------------------------------------------------------------
// Kernel 1: pyramid builder. Each block owns a 64x64 region of the original
// 512x512 image (grid 8x8x8 = 512 blocks) and computes the bicubic /2 cascade
// L1(32x32) -> L2(16x16) -> L3(8x8) for BOTH images entirely in LDS.
// Halo math (taps at src 2i-1..2i+2, edge-clamped):
//   L3 8x8 needs L2 rows [16by-1,16by+17]  (19)
//   L2 19   needs L1 rows [32by-3,32by+36] (40)
//   L1 40   needs src rows [64by-7,64by+74] (82)
// ---------------------------------------------------------------------------
__global__ __launch_bounds__(256) void pyramid_kernel(
    const float* __restrict__ fake, const float* __restrict__ hdr,
    float* __restrict__ f1, float* __restrict__ h1,
    float* __restrict__ f2, float* __restrict__ h2,
    float* __restrict__ f3, float* __restrict__ h3,
    unsigned* __restrict__ counter)
{
    __shared__ float s0[2][82][82];
    __shared__ float l1[2][40][40];
    __shared__ float l2[2][19][19];

    const int tid = threadIdx.x;
    const int bx = blockIdx.x, by = blockIdx.y, bz = blockIdx.z;
    if (bx == 0 && by == 0 && bz == 0 && tid == 0) *counter = 0u;  // for loss kernel

    const float* src0 = fake + (size_t)bz * 512 * 512;
    const float* src1 = hdr  + (size_t)bz * 512 * 512;

    const int oy0 = 64 * by - 7, ox0 = 64 * bx - 7;
    for (int i = tid; i < 2 * 82 * 82; i += 256) {
        const int img = i / (82 * 82), j = i % (82 * 82);
        const int r = j / 82, c = j % 82;
        const int gy = min(max(oy0 + r, 0), 511);
        const int gx = min(max(ox0 + c, 0), 511);
        s0[img][r][c] = (img ? src1 : src0)[(size_t)gy * 512 + gx];
    }
    __syncthreads();

    const float wt0 = -0.09375f, wt1 = 0.59375f;
    const float wt[4] = {wt0, wt1, wt1, wt0};

    // ---- L1: 40x40 region, global rows [32by-3, 32by+37)
    for (int i = tid; i < 2 * 40 * 40; i += 256) {
        const int img = i / 1600, j = i % 1600;
        const int r = j / 40, c = j % 40;
        const int g1y = 32 * by - 3 + r, g1x = 32 * bx - 3 + c;
        int ry[4], cx[4];
#pragma unroll
        for (int k = 0; k < 4; ++k) {
            ry[k] = min(max(2 * g1y - 1 + k, 0), 511) - oy0;
            cx[k] = min(max(2 * g1x - 1 + k, 0), 511) - ox0;
        }
        float a = 0.f;
#pragma unroll
        for (int ky = 0; ky < 4; ++ky) {
            const float* row = s0[img][ry[ky]];
            const float rs = wt0 * (row[cx[0]] + row[cx[3]]) + wt1 * (row[cx[1]] + row[cx[2]]);
            a = fmaf(wt[ky], rs, a);
        }
        l1[img][r][c] = a;
        if (r >= 3 && r < 35 && c >= 3 && c < 35) {
            float* dst = img ? h1 : f1;
            dst[((size_t)bz * 256 + g1y) * 256 + g1x] = a;
        }
    }
    __syncthreads();

    // ---- L2: 19x19 region, global rows [16by-1, 16by+18)
    for (int i = tid; i < 2 * 19 * 19; i += 256) {
        const int img = i / 361, j = i % 361;
        const int r = j / 19, c = j % 19;
        const int g2y = 16 * by - 1 + r, g2x = 16 * bx - 1 + c;
        int ry[4], cx[4];
#pragma unroll
        for (int k = 0; k < 4; ++k) {
            ry[k] = min(max(2 * g2y - 1 + k, 0), 255) - (32 * by - 3);
            cx[k] = min(max(2 * g2x - 1 + k, 0), 255) - (32 * bx - 3);
        }
        float a = 0.f;
#pragma unroll
        for (int ky = 0; ky < 4; ++ky) {
            const float* row = l1[img][ry[ky]];
            const float rs = wt0 * (row[cx[0]] + row[cx[3]]) + wt1 * (row[cx[1]] + row[cx[2]]);
            a = fmaf(wt[ky], rs, a);
        }
        l2[img][r][c] = a;
        if (r >= 1 && r < 17 && c >= 1 && c < 17) {
            float* dst = img ? h2 : f2;
            dst[((size_t)bz * 128 + g2y) * 128 + g2x] = a;
        }
    }
    __syncthreads();

    // ---- L3: 8x8
    for (int i = tid; i < 2 * 8 * 8; i += 256) {
        const int img = i / 64, j = i % 64;
        const int r = j / 8, c = j % 8;
        const int g3y = 8 * by + r, g3x = 8 * bx + c;
        int ry[4], cx[4];
#pragma unroll
        for (int k = 0; k < 4; ++k) {
            ry[k] = min(max(2 * g3y - 1 + k, 0), 127) - (16 * by - 1);
            cx[k] = min(max(2 * g3x - 1 + k, 0), 127) - (16 * bx - 1);
        }
        float a = 0.f;
#pragma unroll
        for (int ky = 0; ky < 4; ++ky) {
            const float* row = l2[img][ry[ky]];
            const float rs = wt0 * (row[cx[0]] + row[cx[3]]) + wt1 * (row[cx[1]] + row[cx[2]]);
            a = fmaf(wt[ky], rs, a);
        }
        float* dst = img ? h3 : f3;
        dst[((size_t)bz * 64 + g3y) * 64 + g3x] = a;
    }
}

// ---------------------------------------------------------------------------
// Kernel 2: ALL levels' bilateral-window MSE partials in one launch.
// 1D grid of 5504 blocks; block id decodes {level, batch, tile}. Tile =
// 128x4 px, 2 px/thread, float2 rw loads. Per-block partial -> unique double
// slot; last finishing block (threadfence+atomic counter) reduces the slots
// and writes the scalar output. No dependencies between blocks except the
// final reduction -> the whole 300 MB streams at full BW.
// ---------------------------------------------------------------------------
__global__ __launch_bounds__(256) void loss_all_kernel(
    const float* __restrict__ fake, const float* __restrict__ hdr,
    const float* __restrict__ window,
    const float* __restrict__ rw0, const float* __restrict__ rw1,
    const float* __restrict__ rw2, const float* __restrict__ rw3,
    const float* __restrict__ f1, const float* __restrict__ h1,
    const float* __restrict__ f2, const float* __restrict__ h2,
    const float* __restrict__ f3, const float* __restrict__ h3,
    double* __restrict__ slots, unsigned* __restrict__ counter,
    float* __restrict__ out)
{
    __shared__ float sf[8][132];
    __shared__ float sh[8][132];
    __shared__ float swin[25];
    __shared__ float wred[4];
    __shared__ double dred[4];
    __shared__ unsigned sdone;

    const int tid = threadIdx.x;
    const int tx = tid & 63, ty = tid >> 6;
    const int lin = blockIdx.x;
    if (tid < 25) swin[tid] = window[tid];

    int S, base;
    const float *F, *H, *RW;
    float scale;
    if (lin < 4096)      { S = 512; F = fake; H = hdr; RW = rw0; scale = 1.00f / (8.f * 512.f * 512.f); base = 0; }
    else if (lin < 5120) { S = 256; F = f1;   H = h1;  RW = rw1; scale = 0.50f / (8.f * 256.f * 256.f); base = 4096; }
    else if (lin < 5376) { S = 128; F = f2;   H = h2;  RW = rw2; scale = 0.25f / (8.f * 128.f * 128.f); base = 5120; }
    else                 { S = 64;  F = f3;   H = h3;  RW = rw3; scale = 0.125f / (8.f * 64.f * 64.f);  base = 5376; }

    const int t   = lin - base;
    const int txT = (S >= 128) ? (S / 128) : 1;
    const int per = txT * (S / 4);
    const int b   = t / per;
    const int r0  = t % per;
    const int by0 = (r0 / txT) * 4;
    const int bx0 = (r0 % txT) * 128;

    const float* Fb = F + (size_t)b * S * S;
    const float* Hb = H + (size_t)b * S * S;

    // halo tile: 8 rows x 132 cols, zero-padded outside the image
    for (int i = tid; i < 8 * 132; i += 256) {
        const int r = i / 132, c = i % 132;
        const int y = by0 + r - 2, x = bx0 + c - 2;
        float fv = 0.f, hv = 0.f;
        if ((unsigned)y < (unsigned)S && (unsigned)x < (unsigned)S) {
            const size_t id = (size_t)y * S + x;
            fv = Fb[id]; hv = Hb[id];
        }
        sf[r][c] = fv; sh[r][c] = hv;
    }
    __syncthreads();

    const int x0 = bx0 + 2 * tx, y = by0 + ty;
    const bool valid = x0 < S;                 // only false at S=64, tx>=32
    const int x0c = valid ? x0 : (S - 2);      // keep loads in-bounds
    const size_t ks = (size_t)S * S;
    const float* rwp = RW + (size_t)b * 25 * ks + (size_t)y * S + x0c;

    float wsum[2] = {0.f, 0.f}, fs[2] = {0.f, 0.f}, hs[2] = {0.f, 0.f};
#pragma unroll
    for (int di = 0; di < 5; ++di) {
        float f6[6], h6[6];
        const float2* pf = (const float2*)&sf[ty + di][2 * tx];
        const float2* ph = (const float2*)&sh[ty + di][2 * tx];
        float2 a = pf[0], bb = pf[1], cc = pf[2];
        f6[0] = a.x; f6[1] = a.y; f6[2] = bb.x; f6[3] = bb.y; f6[4] = cc.x; f6[5] = cc.y;
        float2 d0 = ph[0], e0 = ph[1], g0 = ph[2];
        h6[0] = d0.x; h6[1] = d0.y; h6[2] = e0.x; h6[3] = e0.y; h6[4] = g0.x; h6[5] = g0.y;
#pragma unroll
        for (int dj = 0; dj < 5; ++dj) {
            const int k = di * 5 + dj;
            const float2 rv = *(const float2*)(rwp + (size_t)k * ks);
            const float wm0 = swin[k] * rv.x;
            const float wm1 = swin[k] * rv.y;
            wsum[0] += wm0; wsum[1] += wm1;
            fs[0] = fmaf(wm0, f6[dj], fs[0]);
            fs[1] = fmaf(wm1, f6[dj + 1], fs[1]);
            hs[0] = fmaf(wm0, h6[dj], hs[0]);
            hs[1] = fmaf(wm1, h6[dj + 1], hs[1]);
        }
    }
    float v = 0.f;
    if (valid) {
        const float d0 = (fs[0] - hs[0]) / wsum[0];
        const float d1 = (fs[1] - hs[1]) / wsum[1];
        v = fmaf(d0, d0, d1 * d1);
    }

#pragma unroll
    for (int off = 32; off > 0; off >>= 1) v += __shfl_down(v, off, 64);
    if ((tid & 63) == 0) wred[tid >> 6] = v;
    __syncthreads();
    if (tid == 0) {
        const float sB = wred[0] + wred[1] + wred[2] + wred[3];
        slots[lin] = (double)sB * (double)scale;
        __threadfence();
        sdone = atomicAdd(counter, 1u);
    }
    __syncthreads();

    if (sdone == (unsigned)(gridDim.x - 1)) {   // last block reduces everything
        __threadfence();
        double s = 0.0;
        for (int i = tid; i < 5504; i += 256) s += slots[i];
#pragma unroll
        for (int off = 32; off > 0; off >>= 1) s += __shfl_down(s, off, 64);
        if ((tid & 63) == 0) dred[tid >> 6] = s;
        __syncthreads();
        if (tid == 0) out[0] = (float)(dred[0] + dred[1] + dred[2] + dred[3]);
    }
}

extern "C" void kernel_launch(void* const* d_in, const int* in_sizes, int n_in,
                              void* d_out, int out_size, void* d_ws, size_t ws_size,
                              hipStream_t stream)
{
    const float* fake   = (const float*)d_in[0];
    const float* hdr    = (const float*)d_in[1];
    const float* window = (const float*)d_in[2];
    const float* rw0    = (const float*)d_in[3];
    const float* rw1    = (const float*)d_in[4];
    const float* rw2    = (const float*)d_in[5];
    const float* rw3    = (const float*)d_in[6];
    float* out = (float*)d_out;

    const int B = 8;
    char* ws = (char*)d_ws;
    double* slots     = (double*)ws;             // 5504 doubles = 44 KB
    unsigned* counter = (unsigned*)(ws + 49152);
    float* f1 = (float*)(ws + 65536);
    const size_t n1 = (size_t)B * 256 * 256;
    float* h1 = f1 + n1;
    float* f2 = h1 + n1;
    const size_t n2 = (size_t)B * 128 * 128;
    float* h2 = f2 + n2;
    float* f3 = h2 + n2;
    const size_t n3 = (size_t)B * 64 * 64;
    float* h3 = f3 + n3;

    pyramid_kernel<<<dim3(8, 8, B), 256, 0, stream>>>(
        fake, hdr, f1, h1, f2, h2, f3, h3, counter);

    loss_all_kernel<<<dim3(5504), 256, 0, stream>>>(
        fake, hdr, window, rw0, rw1, rw2, rw3,
        f1, h1, f2, h2, f3, h3, slots, counter, out);
}

// Round 5
// 81.645 us; speedup vs baseline: 3.8769x; 3.8769x over previous
//
#include <hip/hip_runtime.h>
#include <hip/hip_bf16.h>

// ---------------------------------------------------------------------------
// Kernel 1: pyramid builder. Each block owns a 64x64 region of the original
// 512x512 image (grid 8x8x8 = 512 blocks) and computes the bicubic /2 cascade
// L1(32x32) -> L2(16x16) -> L3(8x8) for BOTH images entirely in LDS.
// Halo math (taps at src 2i-1..2i+2, edge-clamped):
//   L3 8x8 needs L2 rows [16by-1,16by+17]  (19)
//   L2 19   needs L1 rows [32by-3,32by+36] (40)
//   L1 40   needs src rows [64by-7,64by+74] (82)
// ---------------------------------------------------------------------------
__global__ __launch_bounds__(256) void pyramid_kernel(
    const float* __restrict__ fake, const float* __restrict__ hdr,
    float* __restrict__ f1, float* __restrict__ h1,
    float* __restrict__ f2, float* __restrict__ h2,
    float* __restrict__ f3, float* __restrict__ h3)
{
    __shared__ float s0[2][82][82];
    __shared__ float l1[2][40][40];
    __shared__ float l2[2][19][19];

    const int tid = threadIdx.x;
    const int bx = blockIdx.x, by = blockIdx.y, bz = blockIdx.z;

    const float* src0 = fake + (size_t)bz * 512 * 512;
    const float* src1 = hdr  + (size_t)bz * 512 * 512;

    const int oy0 = 64 * by - 7, ox0 = 64 * bx - 7;
    for (int i = tid; i < 2 * 82 * 82; i += 256) {
        const int img = i / (82 * 82), j = i % (82 * 82);
        const int r = j / 82, c = j % 82;
        const int gy = min(max(oy0 + r, 0), 511);
        const int gx = min(max(ox0 + c, 0), 511);
        s0[img][r][c] = (img ? src1 : src0)[(size_t)gy * 512 + gx];
    }
    __syncthreads();

    const float wt0 = -0.09375f, wt1 = 0.59375f;
    const float wt[4] = {wt0, wt1, wt1, wt0};

    // ---- L1: 40x40 region, global rows [32by-3, 32by+37)
    for (int i = tid; i < 2 * 40 * 40; i += 256) {
        const int img = i / 1600, j = i % 1600;
        const int r = j / 40, c = j % 40;
        const int g1y = 32 * by - 3 + r, g1x = 32 * bx - 3 + c;
        int ry[4], cx[4];
#pragma unroll
        for (int k = 0; k < 4; ++k) {
            ry[k] = min(max(2 * g1y - 1 + k, 0), 511) - oy0;
            cx[k] = min(max(2 * g1x - 1 + k, 0), 511) - ox0;
        }
        float a = 0.f;
#pragma unroll
        for (int ky = 0; ky < 4; ++ky) {
            const float* row = s0[img][ry[ky]];
            const float rs = wt0 * (row[cx[0]] + row[cx[3]]) + wt1 * (row[cx[1]] + row[cx[2]]);
            a = fmaf(wt[ky], rs, a);
        }
        l1[img][r][c] = a;
        if (r >= 3 && r < 35 && c >= 3 && c < 35) {
            float* dst = img ? h1 : f1;
            dst[((size_t)bz * 256 + g1y) * 256 + g1x] = a;
        }
    }
    __syncthreads();

    // ---- L2: 19x19 region, global rows [16by-1, 16by+18)
    for (int i = tid; i < 2 * 19 * 19; i += 256) {
        const int img = i / 361, j = i % 361;
        const int r = j / 19, c = j % 19;
        const int g2y = 16 * by - 1 + r, g2x = 16 * bx - 1 + c;
        int ry[4], cx[4];
#pragma unroll
        for (int k = 0; k < 4; ++k) {
            ry[k] = min(max(2 * g2y - 1 + k, 0), 255) - (32 * by - 3);
            cx[k] = min(max(2 * g2x - 1 + k, 0), 255) - (32 * bx - 3);
        }
        float a = 0.f;
#pragma unroll
        for (int ky = 0; ky < 4; ++ky) {
            const float* row = l1[img][ry[ky]];
            const float rs = wt0 * (row[cx[0]] + row[cx[3]]) + wt1 * (row[cx[1]] + row[cx[2]]);
            a = fmaf(wt[ky], rs, a);
        }
        l2[img][r][c] = a;
        if (r >= 1 && r < 17 && c >= 1 && c < 17) {
            float* dst = img ? h2 : f2;
            dst[((size_t)bz * 128 + g2y) * 128 + g2x] = a;
        }
    }
    __syncthreads();

    // ---- L3: 8x8
    for (int i = tid; i < 2 * 8 * 8; i += 256) {
        const int img = i / 64, j = i % 64;
        const int r = j / 8, c = j % 8;
        const int g3y = 8 * by + r, g3x = 8 * bx + c;
        int ry[4], cx[4];
#pragma unroll
        for (int k = 0; k < 4; ++k) {
            ry[k] = min(max(2 * g3y - 1 + k, 0), 127) - (16 * by - 1);
            cx[k] = min(max(2 * g3x - 1 + k, 0), 127) - (16 * bx - 1);
        }
        float a = 0.f;
#pragma unroll
        for (int ky = 0; ky < 4; ++ky) {
            const float* row = l2[img][ry[ky]];
            const float rs = wt0 * (row[cx[0]] + row[cx[3]]) + wt1 * (row[cx[1]] + row[cx[2]]);
            a = fmaf(wt[ky], rs, a);
        }
        float* dst = img ? h3 : f3;
        dst[((size_t)bz * 64 + g3y) * 64 + g3x] = a;
    }
}

// ---------------------------------------------------------------------------
// Kernel 2: ALL levels' bilateral-window MSE partials in one launch.
// 1D grid of 5504 blocks; block id decodes {level, batch, tile}. Tile =
// 128x4 px, 2 px/thread, float2 rw loads. Per-block partial -> unique double
// slot, then the block EXITS (no fence, no atomic — R4's single-counter +
// threadfence exit protocol serialized all 5504 blocks and cost 290us).
// ---------------------------------------------------------------------------
__global__ __launch_bounds__(256) void loss_all_kernel(
    const float* __restrict__ fake, const float* __restrict__ hdr,
    const float* __restrict__ window,
    const float* __restrict__ rw0, const float* __restrict__ rw1,
    const float* __restrict__ rw2, const float* __restrict__ rw3,
    const float* __restrict__ f1, const float* __restrict__ h1,
    const float* __restrict__ f2, const float* __restrict__ h2,
    const float* __restrict__ f3, const float* __restrict__ h3,
    double* __restrict__ slots)
{
    __shared__ float sf[8][132];
    __shared__ float sh[8][132];
    __shared__ float swin[25];
    __shared__ float wred[4];

    const int tid = threadIdx.x;
    const int tx = tid & 63, ty = tid >> 6;
    const int lin = blockIdx.x;
    if (tid < 25) swin[tid] = window[tid];

    int S, base;
    const float *F, *H, *RW;
    float scale;
    if (lin < 4096)      { S = 512; F = fake; H = hdr; RW = rw0; scale = 1.00f / (8.f * 512.f * 512.f); base = 0; }
    else if (lin < 5120) { S = 256; F = f1;   H = h1;  RW = rw1; scale = 0.50f / (8.f * 256.f * 256.f); base = 4096; }
    else if (lin < 5376) { S = 128; F = f2;   H = h2;  RW = rw2; scale = 0.25f / (8.f * 128.f * 128.f); base = 5120; }
    else                 { S = 64;  F = f3;   H = h3;  RW = rw3; scale = 0.125f / (8.f * 64.f * 64.f);  base = 5376; }

    const int t   = lin - base;
    const int txT = (S >= 128) ? (S / 128) : 1;
    const int per = txT * (S / 4);
    const int b   = t / per;
    const int r0  = t % per;
    const int by0 = (r0 / txT) * 4;
    const int bx0 = (r0 % txT) * 128;

    const float* Fb = F + (size_t)b * S * S;
    const float* Hb = H + (size_t)b * S * S;

    // halo tile: 8 rows x 132 cols, zero-padded outside the image
    for (int i = tid; i < 8 * 132; i += 256) {
        const int r = i / 132, c = i % 132;
        const int y = by0 + r - 2, x = bx0 + c - 2;
        float fv = 0.f, hv = 0.f;
        if ((unsigned)y < (unsigned)S && (unsigned)x < (unsigned)S) {
            const size_t id = (size_t)y * S + x;
            fv = Fb[id]; hv = Hb[id];
        }
        sf[r][c] = fv; sh[r][c] = hv;
    }
    __syncthreads();

    const int x0 = bx0 + 2 * tx, y = by0 + ty;
    const bool valid = x0 < S;                 // only false at S=64, tx>=32
    const int x0c = valid ? x0 : (S - 2);      // keep loads in-bounds
    const size_t ks = (size_t)S * S;
    const float* rwp = RW + (size_t)b * 25 * ks + (size_t)y * S + x0c;

    float wsum[2] = {0.f, 0.f}, fs[2] = {0.f, 0.f}, hs[2] = {0.f, 0.f};
#pragma unroll
    for (int di = 0; di < 5; ++di) {
        float f6[6], h6[6];
        const float2* pf = (const float2*)&sf[ty + di][2 * tx];
        const float2* ph = (const float2*)&sh[ty + di][2 * tx];
        float2 a = pf[0], bb = pf[1], cc = pf[2];
        f6[0] = a.x; f6[1] = a.y; f6[2] = bb.x; f6[3] = bb.y; f6[4] = cc.x; f6[5] = cc.y;
        float2 d0 = ph[0], e0 = ph[1], g0 = ph[2];
        h6[0] = d0.x; h6[1] = d0.y; h6[2] = e0.x; h6[3] = e0.y; h6[4] = g0.x; h6[5] = g0.y;
#pragma unroll
        for (int dj = 0; dj < 5; ++dj) {
            const int k = di * 5 + dj;
            const float2 rv = *(const float2*)(rwp + (size_t)k * ks);
            const float wm0 = swin[k] * rv.x;
            const float wm1 = swin[k] * rv.y;
            wsum[0] += wm0; wsum[1] += wm1;
            fs[0] = fmaf(wm0, f6[dj], fs[0]);
            fs[1] = fmaf(wm1, f6[dj + 1], fs[1]);
            hs[0] = fmaf(wm0, h6[dj], hs[0]);
            hs[1] = fmaf(wm1, h6[dj + 1], hs[1]);
        }
    }
    float v = 0.f;
    if (valid) {
        const float d0 = (fs[0] - hs[0]) / wsum[0];
        const float d1 = (fs[1] - hs[1]) / wsum[1];
        v = fmaf(d0, d0, d1 * d1);
    }

#pragma unroll
    for (int off = 32; off > 0; off >>= 1) v += __shfl_down(v, off, 64);
    if ((tid & 63) == 0) wred[tid >> 6] = v;
    __syncthreads();
    if (tid == 0) {
        const float sB = wred[0] + wred[1] + wred[2] + wred[3];
        slots[lin] = (double)sB * (double)scale;
    }
}

__global__ void finalize_kernel(const double* __restrict__ slots, float* __restrict__ out, int n)
{
    __shared__ double dred[4];
    const int t = threadIdx.x;  // 256 threads
    double s = 0.0;
    for (int i = t; i < n; i += 256) s += slots[i];
#pragma unroll
    for (int off = 32; off > 0; off >>= 1) s += __shfl_down(s, off, 64);
    if ((t & 63) == 0) dred[t >> 6] = s;
    __syncthreads();
    if (t == 0) out[0] = (float)(dred[0] + dred[1] + dred[2] + dred[3]);
}

extern "C" void kernel_launch(void* const* d_in, const int* in_sizes, int n_in,
                              void* d_out, int out_size, void* d_ws, size_t ws_size,
                              hipStream_t stream)
{
    const float* fake   = (const float*)d_in[0];
    const float* hdr    = (const float*)d_in[1];
    const float* window = (const float*)d_in[2];
    const float* rw0    = (const float*)d_in[3];
    const float* rw1    = (const float*)d_in[4];
    const float* rw2    = (const float*)d_in[5];
    const float* rw3    = (const float*)d_in[6];
    float* out = (float*)d_out;

    const int B = 8;
    char* ws = (char*)d_ws;
    double* slots = (double*)ws;                 // 5504 doubles = 44 KB
    float* f1 = (float*)(ws + 65536);
    const size_t n1 = (size_t)B * 256 * 256;
    float* h1 = f1 + n1;
    float* f2 = h1 + n1;
    const size_t n2 = (size_t)B * 128 * 128;
    float* h2 = f2 + n2;
    float* f3 = h2 + n2;
    const size_t n3 = (size_t)B * 64 * 64;
    float* h3 = f3 + n3;

    pyramid_kernel<<<dim3(8, 8, B), 256, 0, stream>>>(
        fake, hdr, f1, h1, f2, h2, f3, h3);

    loss_all_kernel<<<dim3(5504), 256, 0, stream>>>(
        fake, hdr, window, rw0, rw1, rw2, rw3,
        f1, h1, f2, h2, f3, h3, slots);

    finalize_kernel<<<1, 256, 0, stream>>>(slots, out, 5504);
}

// Round 6
// 70.250 us; speedup vs baseline: 4.5058x; 1.1622x over previous
//
#include <hip/hip_runtime.h>
#include <hip/hip_bf16.h>

#define WT0 (-0.09375f)
#define WT1 (0.59375f)

// ---------------------------------------------------------------------------
// K1/K2: fused loss (level k) + bicubic/2 downsample (level k+1 image build).
// Tile 256x4 px, 256 threads, 4 px/thread, float4 rw loads (16 B/lane).
// Block partial -> unique double slot (no atomics, no zero-init).
// ---------------------------------------------------------------------------
template <int S>
__global__ __launch_bounds__(256) void loss_down_kernel(
    const float* __restrict__ F0, const float* __restrict__ H0,
    const float* __restrict__ window, const float* __restrict__ RW,
    double* __restrict__ slots, float scale,
    float* __restrict__ fd, float* __restrict__ hd)
{
    constexpr int TW = 256;
    __shared__ __align__(16) float sf[8][TW + 4];
    __shared__ __align__(16) float sh[8][TW + 4];
    __shared__ float swin[25];
    __shared__ float wred[4];

    const int tid = threadIdx.x;
    const int tx = tid & 63, ty = tid >> 6;
    if (tid < 25) swin[tid] = window[tid];

    const int bx0 = blockIdx.x * TW;
    const int by0 = blockIdx.y * 4;
    const int b   = blockIdx.z;

    const float* Fb = F0 + (size_t)b * S * S;
    const float* Hb = H0 + (size_t)b * S * S;

    // stage 8 x 260 halo tile, zero-padded outside the image
    for (int i = tid; i < 8 * (TW + 4); i += 256) {
        const int r = i / (TW + 4), c = i % (TW + 4);
        const int y = by0 + r - 2, x = bx0 + c - 2;
        float fv = 0.f, hv = 0.f;
        if ((unsigned)y < (unsigned)S && (unsigned)x < (unsigned)S) {
            const size_t id = (size_t)y * S + x;
            fv = Fb[id]; hv = Hb[id];
        }
        sf[r][c] = fv; sh[r][c] = hv;
    }
    __syncthreads();

    const int x0 = bx0 + 4 * tx, y = by0 + ty;
    const size_t ks = (size_t)S * S;
    const float* rwp = RW + (size_t)b * 25 * ks + (size_t)y * S + x0;

    float wsum[4] = {0.f, 0.f, 0.f, 0.f};
    float fs[4]   = {0.f, 0.f, 0.f, 0.f};
    float hs[4]   = {0.f, 0.f, 0.f, 0.f};
#pragma unroll
    for (int di = 0; di < 5; ++di) {
        float f9[9], h9[9];
        {
            const float4* pf = (const float4*)&sf[ty + di][4 * tx];
            const float4 a0 = pf[0], a1 = pf[1];
            f9[0]=a0.x; f9[1]=a0.y; f9[2]=a0.z; f9[3]=a0.w;
            f9[4]=a1.x; f9[5]=a1.y; f9[6]=a1.z; f9[7]=a1.w;
            f9[8]=sf[ty + di][4 * tx + 8];
            const float4* ph = (const float4*)&sh[ty + di][4 * tx];
            const float4 b0 = ph[0], b1 = ph[1];
            h9[0]=b0.x; h9[1]=b0.y; h9[2]=b0.z; h9[3]=b0.w;
            h9[4]=b1.x; h9[5]=b1.y; h9[6]=b1.z; h9[7]=b1.w;
            h9[8]=sh[ty + di][4 * tx + 8];
        }
#pragma unroll
        for (int dj = 0; dj < 5; ++dj) {
            const int k = di * 5 + dj;
            const float4 rv = *(const float4*)(rwp + (size_t)k * ks);
            const float w0 = swin[k] * rv.x;
            const float w1 = swin[k] * rv.y;
            const float w2 = swin[k] * rv.z;
            const float w3 = swin[k] * rv.w;
            wsum[0] += w0; wsum[1] += w1; wsum[2] += w2; wsum[3] += w3;
            fs[0] = fmaf(w0, f9[dj + 0], fs[0]);
            fs[1] = fmaf(w1, f9[dj + 1], fs[1]);
            fs[2] = fmaf(w2, f9[dj + 2], fs[2]);
            fs[3] = fmaf(w3, f9[dj + 3], fs[3]);
            hs[0] = fmaf(w0, h9[dj + 0], hs[0]);
            hs[1] = fmaf(w1, h9[dj + 1], hs[1]);
            hs[2] = fmaf(w2, h9[dj + 2], hs[2]);
            hs[3] = fmaf(w3, h9[dj + 3], hs[3]);
        }
    }
    float v = 0.f;
#pragma unroll
    for (int p = 0; p < 4; ++p) {
        const float d = (fs[p] - hs[p]) / wsum[p];
        v = fmaf(d, d, v);
    }
#pragma unroll
    for (int off = 32; off > 0; off >>= 1) v += __shfl_down(v, off, 64);
    if ((tid & 63) == 0) wred[tid >> 6] = v;

    // fused bicubic /2 (edge-clamped taps at src 2i-1..2i+2) from LDS tile:
    // 2 rows x 128 cols per image. Clamped coords always land on real pixels
    // inside the tile (never the zero-pad entries).
    {
        constexpr int Sh = S / 2;
        const float wt[4] = {WT0, WT1, WT1, WT0};
        for (int i = tid; i < 512; i += 256) {
            const int img = i >> 8, t2 = i & 255;
            const int r = t2 >> 7, c = t2 & 127;
            const int g1y = (by0 >> 1) + r, g1x = (bx0 >> 1) + c;
            float (*s)[TW + 4] = img ? sh : sf;
            int lc[4];
#pragma unroll
            for (int kx = 0; kx < 4; ++kx)
                lc[kx] = min(max(bx0 + 2 * c - 1 + kx, 0), S - 1) - bx0 + 2;
            float acc = 0.f;
#pragma unroll
            for (int ky = 0; ky < 4; ++ky) {
                const int lr = min(max(by0 + 2 * r - 1 + ky, 0), S - 1) - by0 + 2;
                const float rs = WT0 * (s[lr][lc[0]] + s[lr][lc[3]])
                               + WT1 * (s[lr][lc[1]] + s[lr][lc[2]]);
                acc = fmaf(wt[ky], rs, acc);
            }
            float* dst = img ? hd : fd;
            dst[((size_t)b * Sh + g1y) * Sh + g1x] = acc;
        }
    }

    __syncthreads();
    if (tid == 0) {
        const float sB = wred[0] + wred[1] + wred[2] + wred[3];
        const unsigned lin = blockIdx.x + gridDim.x * (blockIdx.y + gridDim.y * blockIdx.z);
        slots[lin] = (double)sB * (double)scale;
    }
}

// ---------------------------------------------------------------------------
// K3: levels 2 and 3 in one launch (384 blocks).
//   lin <  256: level-2 loss. S=128, tile 128x4, 2 px/thread, float2 loads.
//   lin >= 256: level-3 loss. S=64, tile 64x4. Block rebuilds its L3 tile
//               locally from f2/h2 (18x128 stage -> 8x68 L3), avoiding the
//               global f3 round-trip and an extra kernel launch.
// ---------------------------------------------------------------------------
__global__ __launch_bounds__(256) void loss_tail_kernel(
    const float* __restrict__ window,
    const float* __restrict__ rw2, const float* __restrict__ rw3,
    const float* __restrict__ f2, const float* __restrict__ h2,
    double* __restrict__ slots)
{
    __shared__ float s2f[8][132];
    __shared__ float s2h[8][132];
    __shared__ float p2[2][18][128];
    __shared__ float l3[2][8][68];
    __shared__ float swin[25];
    __shared__ float wred[4];

    const int tid = threadIdx.x;
    const int tx = tid & 63, ty = tid >> 6;
    if (tid < 25) swin[tid] = window[tid];
    const int lin = blockIdx.x;

    float v = 0.f;
    float scale;

    if (lin < 256) {
        // ----- level 2: S = 128 -----
        const int b = lin >> 5, by0 = (lin & 31) * 4;
        const float* Fb = f2 + (size_t)b * 128 * 128;
        const float* Hb = h2 + (size_t)b * 128 * 128;
        for (int i = tid; i < 8 * 132; i += 256) {
            const int r = i / 132, c = i % 132;
            const int y = by0 + r - 2, x = c - 2;
            float fv = 0.f, hv = 0.f;
            if ((unsigned)y < 128u && (unsigned)x < 128u) {
                const size_t id = (size_t)y * 128 + x;
                fv = Fb[id]; hv = Hb[id];
            }
            s2f[r][c] = fv; s2h[r][c] = hv;
        }
        __syncthreads();

        const int x0 = 2 * tx, y = by0 + ty;
        const size_t ks = 128 * 128;
        const float* rwp = rw2 + (size_t)b * 25 * ks + (size_t)y * 128 + x0;
        float wsum[2] = {0.f, 0.f}, fs[2] = {0.f, 0.f}, hs[2] = {0.f, 0.f};
#pragma unroll
        for (int di = 0; di < 5; ++di) {
            float f6[6], h6[6];
            const float2* pf = (const float2*)&s2f[ty + di][2 * tx];
            const float2 a0 = pf[0], a1 = pf[1], a2 = pf[2];
            f6[0]=a0.x; f6[1]=a0.y; f6[2]=a1.x; f6[3]=a1.y; f6[4]=a2.x; f6[5]=a2.y;
            const float2* ph = (const float2*)&s2h[ty + di][2 * tx];
            const float2 b0 = ph[0], b1 = ph[1], b2 = ph[2];
            h6[0]=b0.x; h6[1]=b0.y; h6[2]=b1.x; h6[3]=b1.y; h6[4]=b2.x; h6[5]=b2.y;
#pragma unroll
            for (int dj = 0; dj < 5; ++dj) {
                const int k = di * 5 + dj;
                const float2 rv = *(const float2*)(rwp + (size_t)k * ks);
                const float w0 = swin[k] * rv.x;
                const float w1 = swin[k] * rv.y;
                wsum[0] += w0; wsum[1] += w1;
                fs[0] = fmaf(w0, f6[dj + 0], fs[0]);
                fs[1] = fmaf(w1, f6[dj + 1], fs[1]);
                hs[0] = fmaf(w0, h6[dj + 0], hs[0]);
                hs[1] = fmaf(w1, h6[dj + 1], hs[1]);
            }
        }
        const float d0 = (fs[0] - hs[0]) / wsum[0];
        const float d1 = (fs[1] - hs[1]) / wsum[1];
        v = fmaf(d0, d0, d1 * d1);
        scale = 0.25f / (8.f * 128.f * 128.f);
    } else {
        // ----- level 3: S = 64, rebuild L3 locally from f2/h2 -----
        const int t = lin - 256;
        const int b = t >> 4, by0 = (t & 15) * 4;
        const int fr0 = 2 * by0 - 5;   // first (unclamped) f2 row we stage
        for (int i = tid; i < 2 * 18 * 128; i += 256) {
            const int img = i / 2304, j = i % 2304;
            const int r = j >> 7, c = j & 127;
            const int gy = min(max(fr0 + r, 0), 127);
            p2[img][r][c] = (img ? h2 : f2)[((size_t)b * 128 + gy) * 128 + c];
        }
        __syncthreads();
        // build L3 tile rows [by0-2, by0+6), cols [-2, 66), zero-pad outside
        const float wt[4] = {WT0, WT1, WT1, WT0};
        for (int i = tid; i < 2 * 8 * 68; i += 256) {
            const int img = i / 544, j = i % 544;
            const int r = j / 68, c = j % 68;
            const int gy = by0 - 2 + r, gx = c - 2;
            float a = 0.f;
            if ((unsigned)gy < 64u && (unsigned)gx < 64u) {
                int ry[4], cx[4];
#pragma unroll
                for (int k = 0; k < 4; ++k) {
                    ry[k] = min(max(2 * gy - 1 + k, 0), 127) - fr0;
                    cx[k] = min(max(2 * gx - 1 + k, 0), 127);
                }
#pragma unroll
                for (int ky = 0; ky < 4; ++ky) {
                    const float* row = p2[img][ry[ky]];
                    const float rs = WT0 * (row[cx[0]] + row[cx[3]])
                                   + WT1 * (row[cx[1]] + row[cx[2]]);
                    a = fmaf(wt[ky], rs, a);
                }
            }
            l3[img][r][c] = a;
        }
        __syncthreads();

        const size_t ks = 64 * 64;
        const float* rwp = rw3 + (size_t)b * 25 * ks + (size_t)(by0 + ty) * 64 + tx;
        float wsum = 0.f, fs = 0.f, hs = 0.f;
#pragma unroll
        for (int di = 0; di < 5; ++di) {
#pragma unroll
            for (int dj = 0; dj < 5; ++dj) {
                const int k = di * 5 + dj;
                const float wm = swin[k] * rwp[(size_t)k * ks];
                wsum += wm;
                fs = fmaf(wm, l3[0][ty + di][tx + dj], fs);
                hs = fmaf(wm, l3[1][ty + di][tx + dj], hs);
            }
        }
        const float d = (fs - hs) / wsum;
        v = d * d;
        scale = 0.125f / (8.f * 64.f * 64.f);
    }

#pragma unroll
    for (int off = 32; off > 0; off >>= 1) v += __shfl_down(v, off, 64);
    if ((tid & 63) == 0) wred[tid >> 6] = v;
    __syncthreads();
    if (tid == 0) {
        const float sB = wred[0] + wred[1] + wred[2] + wred[3];
        slots[lin] = (double)sB * (double)scale;
    }
}

__global__ void finalize_kernel(const double* __restrict__ slots, float* __restrict__ out, int n)
{
    __shared__ double dred[4];
    const int t = threadIdx.x;  // 256 threads
    double s = 0.0;
    for (int i = t; i < n; i += 256) s += slots[i];
#pragma unroll
    for (int off = 32; off > 0; off >>= 1) s += __shfl_down(s, off, 64);
    if ((t & 63) == 0) dred[t >> 6] = s;
    __syncthreads();
    if (t == 0) out[0] = (float)(dred[0] + dred[1] + dred[2] + dred[3]);
}

extern "C" void kernel_launch(void* const* d_in, const int* in_sizes, int n_in,
                              void* d_out, int out_size, void* d_ws, size_t ws_size,
                              hipStream_t stream)
{
    const float* fake   = (const float*)d_in[0];
    const float* hdr    = (const float*)d_in[1];
    const float* window = (const float*)d_in[2];
    const float* rw0    = (const float*)d_in[3];
    const float* rw1    = (const float*)d_in[4];
    const float* rw2    = (const float*)d_in[5];
    const float* rw3    = (const float*)d_in[6];
    float* out = (float*)d_out;

    const int B = 8;
    char* ws = (char*)d_ws;
    double* slots = (double*)ws;                 // 2944 doubles, all stored
    float* f1 = (float*)(ws + 32768);
    const size_t n1 = (size_t)B * 256 * 256;
    float* h1 = f1 + n1;
    float* f2 = h1 + n1;
    const size_t n2 = (size_t)B * 128 * 128;
    float* h2 = f2 + n2;

    // K1: level-0 loss + L1 build. 2048 blocks (exactly 8/CU, no tail).
    loss_down_kernel<512><<<dim3(2, 128, B), 256, 0, stream>>>(
        fake, hdr, window, rw0, slots, 1.0f / (8.f * 512.f * 512.f), f1, h1);

    // K2: level-1 loss + L2 build. 512 blocks.
    loss_down_kernel<256><<<dim3(1, 64, B), 256, 0, stream>>>(
        f1, h1, window, rw1, slots + 2048, 0.5f / (8.f * 256.f * 256.f), f2, h2);

    // K3: level-2 + level-3 loss (local L3 rebuild). 384 blocks.
    loss_tail_kernel<<<dim3(384), 256, 0, stream>>>(
        window, rw2, rw3, f2, h2, slots + 2560);

    // K4: final reduction of 2944 slots.
    finalize_kernel<<<1, 256, 0, stream>>>(slots, out, 2944);
}